// Round 4
// baseline (3240.434 us; speedup 1.0000x reference)
//
#include <hip/hip_runtime.h>

#define LNUM 8
#define WD 128
#define BATCH 262144
#define BLK 512

typedef unsigned int u32;
typedef __attribute__((ext_vector_type(8))) short bf16x8;
typedef __attribute__((ext_vector_type(4))) float f32x4;

// packed f32x2 -> bf16x2 (single VALU op; T12 recipe — no builtin on gfx950)
__device__ __forceinline__ u32 pk2(float x, float y){
  u32 r;
  asm("v_cvt_pk_bf16_f32 %0, %1, %2" : "=v"(r) : "v"(x), "v"(y));
  return r;
}

// Stage a 128x128 fp32 weight matrix into LDS as bf16, row-major, XOR-swizzled
// (4-dword granularity: dword ^ ((row&7)<<2)). 512 threads: row j=t>>2, quarter q=t&3.
__device__ __forceinline__ void stage_W(const float* __restrict__ src, u32* dst, int tid){
  const int j = tid >> 2, q = tid & 3;
  const float* s = src + j * WD + q * 32;
  u32* drow = dst + j * 64;
  const int base = q * 16;
  const u32 sz = (u32)((j & 7) << 2);
#pragma unroll
  for(int c = 0; c < 4; ++c){
    float4 f0 = *(const float4*)(s + c * 8);
    float4 f1 = *(const float4*)(s + c * 8 + 4);
    uint4 w;
    w.x = pk2(f0.x, f0.y); w.y = pk2(f0.z, f0.w);
    w.z = pk2(f1.x, f1.y); w.w = pk2(f1.z, f1.w);
    *(uint4*)(drow + (((u32)(base + c * 4)) ^ sz)) = w;
  }
}

// Full 4-stage MLP for one wave's 64 samples, hidden state entirely in registers.
// Returns pre-activation (before +b4, tanh) for this thread's own sample.
//
// mid1 uses the natural k-map: slot (lg,e) <-> k = kt*32 + lg*8 + e   (A: b128 read)
// mid2 uses a permuted k-map: slot (lg,e) <-> k = kt*32 + (e>>2)*16 + lg*4 + (e&3)
//   chosen so the B-fragment is the lane's OWN tr[] dwords (no cross-lane ops);
//   A reads W3 with the matching permutation (2x ds_read_b64). MFMA contracts
//   slot-wise with identical A/B slot->k maps, so any consistent bijection is valid.
__device__ __forceinline__ float mlp_frag(
    float u, const u32* __restrict__ W2lds, const u32* __restrict__ W3lds,
    const float* __restrict__ W1, const float* __restrict__ b1,
    const float* __restrict__ b2, const float* __restrict__ b3,
    const float* __restrict__ W4, int lm, int lg)
{
  // broadcast u of sample st*16+lm into every lane
  float ust[4];
#pragma unroll
  for(int st = 0; st < 4; ++st) ust[st] = __shfl(u, st * 16 + lm, 64);

  const f32x4 zero = {0.f, 0.f, 0.f, 0.f};
  f32x4 acc1[8][4];
#pragma unroll
  for(int jt = 0; jt < 8; ++jt)
#pragma unroll
    for(int st = 0; st < 4; ++st) acc1[jt][st] = zero;

  // ---- stage1 (build B-frags directly) + mid1: acc1 = W2 * H1^T ----
#pragma unroll
  for(int kt = 0; kt < 4; ++kt){
    const int ko = kt * 32 + lg * 8;      // k = ko + e, e=0..7
    const float4 w1a = *(const float4*)(W1 + ko);
    const float4 w1b = *(const float4*)(W1 + ko + 4);
    const float4 g1a = *(const float4*)(b1 + ko);
    const float4 g1b = *(const float4*)(b1 + ko + 4);
    bf16x8 bv[4];
#pragma unroll
    for(int st = 0; st < 4; ++st){
      const float uv = ust[st];
      float h0 = fmaxf(fmaf(uv, w1a.x, g1a.x), 0.f);
      float h1 = fmaxf(fmaf(uv, w1a.y, g1a.y), 0.f);
      float h2 = fmaxf(fmaf(uv, w1a.z, g1a.z), 0.f);
      float h3 = fmaxf(fmaf(uv, w1a.w, g1a.w), 0.f);
      float h4 = fmaxf(fmaf(uv, w1b.x, g1b.x), 0.f);
      float h5 = fmaxf(fmaf(uv, w1b.y, g1b.y), 0.f);
      float h6 = fmaxf(fmaf(uv, w1b.z, g1b.z), 0.f);
      float h7 = fmaxf(fmaf(uv, w1b.w, g1b.w), 0.f);
      uint4 pk;
      pk.x = pk2(h0, h1); pk.y = pk2(h2, h3);
      pk.z = pk2(h4, h5); pk.w = pk2(h6, h7);
      bv[st] = __builtin_bit_cast(bf16x8, pk);
    }
    const u32 kdw = (u32)(kt * 16 + lg * 4);
#pragma unroll
    for(int jt = 0; jt < 8; ++jt){
      const int j = lm + 16 * jt;
      bf16x8 av = __builtin_bit_cast(bf16x8,
          *(const uint4*)(W2lds + j * 64 + (kdw ^ (u32)((j & 7) << 2))));
#pragma unroll
      for(int st = 0; st < 4; ++st)
        acc1[jt][st] = __builtin_amdgcn_mfma_f32_16x16x32_bf16(av, bv[st], acc1[jt][st], 0, 0, 0);
    }
  }

  // ---- transition: bias+relu+pack; tr[jt][st][d] holds (j=jt*16+lg*4+2d, +1) ----
  u32 tr[8][4][2];
#pragma unroll
  for(int jt = 0; jt < 8; ++jt){
    const float4 bb = *(const float4*)(b2 + jt * 16 + lg * 4);
#pragma unroll
    for(int st = 0; st < 4; ++st){
      float h0 = fmaxf(acc1[jt][st][0] + bb.x, 0.f);
      float h1 = fmaxf(acc1[jt][st][1] + bb.y, 0.f);
      float h2 = fmaxf(acc1[jt][st][2] + bb.z, 0.f);
      float h3 = fmaxf(acc1[jt][st][3] + bb.w, 0.f);
      tr[jt][st][0] = pk2(h0, h1);
      tr[jt][st][1] = pk2(h2, h3);
    }
  }

  // ---- mid2: acc2 = W3 * H2^T, B-frags from OWN registers (permuted k-map) ----
  f32x4 acc2[8][4];
#pragma unroll
  for(int jt = 0; jt < 8; ++jt)
#pragma unroll
    for(int st = 0; st < 4; ++st) acc2[jt][st] = zero;

#pragma unroll
  for(int kt = 0; kt < 4; ++kt){
    bf16x8 bv[4];
#pragma unroll
    for(int st = 0; st < 4; ++st){
      uint4 pk;
      pk.x = tr[2*kt    ][st][0];
      pk.y = tr[2*kt    ][st][1];
      pk.z = tr[2*kt + 1][st][0];
      pk.w = tr[2*kt + 1][st][1];
      bv[st] = __builtin_bit_cast(bf16x8, pk);
    }
    const u32 o1 = (u32)(kt * 16 + 2 * lg);
#pragma unroll
    for(int jt = 0; jt < 8; ++jt){
      const int j = lm + 16 * jt;
      const u32 sz = (u32)((j & 7) << 2);
      const u32* r = W3lds + j * 64;
      uint2 lo = *(const uint2*)(r + (o1 ^ sz));         // k-pairs lg*4+{0..3}
      uint2 hi = *(const uint2*)(r + ((o1 + 8) ^ sz));   // k-pairs 16+lg*4+{0..3}
      uint4 a4; a4.x = lo.x; a4.y = lo.y; a4.z = hi.x; a4.w = hi.y;
      bf16x8 av = __builtin_bit_cast(bf16x8, a4);
#pragma unroll
      for(int st = 0; st < 4; ++st)
        acc2[jt][st] = __builtin_amdgcn_mfma_f32_16x16x32_bf16(av, bv[st], acc2[jt][st], 0, 0, 0);
    }
  }

  // ---- out: dot(relu(acc2+b3), W4) with lg-butterfly reduction ----
  float p0 = 0.f, p1 = 0.f, p2 = 0.f, p3 = 0.f;
#pragma unroll
  for(int jt = 0; jt < 8; ++jt){
    const float4 bc = *(const float4*)(b3 + jt * 16 + lg * 4);
    const float4 wc = *(const float4*)(W4 + jt * 16 + lg * 4);
#pragma unroll
    for(int st = 0; st < 4; ++st){
      float q = (st == 0) ? p0 : (st == 1) ? p1 : (st == 2) ? p2 : p3;
      q = fmaf(fmaxf(acc2[jt][st][0] + bc.x, 0.f), wc.x, q);
      q = fmaf(fmaxf(acc2[jt][st][1] + bc.y, 0.f), wc.y, q);
      q = fmaf(fmaxf(acc2[jt][st][2] + bc.z, 0.f), wc.z, q);
      q = fmaf(fmaxf(acc2[jt][st][3] + bc.w, 0.f), wc.w, q);
      if(st == 0) p0 = q; else if(st == 1) p1 = q; else if(st == 2) p2 = q; else p3 = q;
    }
  }
  p0 += __shfl_xor(p0, 16, 64); p0 += __shfl_xor(p0, 32, 64);
  p1 += __shfl_xor(p1, 16, 64); p1 += __shfl_xor(p1, 32, 64);
  p2 += __shfl_xor(p2, 16, 64); p2 += __shfl_xor(p2, 32, 64);
  p3 += __shfl_xor(p3, 16, 64); p3 += __shfl_xor(p3, 32, 64);
  return (lg == 0) ? p0 : (lg == 1) ? p1 : (lg == 2) ? p2 : p3;
}

extern "C" __global__ void __launch_bounds__(BLK, 4)
flow_kernel(const float* __restrict__ x, const float* __restrict__ s_scale,
            const float* __restrict__ sW1, const float* __restrict__ sb1,
            const float* __restrict__ sW2, const float* __restrict__ sb2,
            const float* __restrict__ sW3, const float* __restrict__ sb3,
            const float* __restrict__ sW4, const float* __restrict__ sb4,
            const float* __restrict__ tW1, const float* __restrict__ tb1,
            const float* __restrict__ tW2, const float* __restrict__ tb2,
            const float* __restrict__ tW3, const float* __restrict__ tb3,
            const float* __restrict__ tW4, const float* __restrict__ tb4,
            float* __restrict__ out)
{
  __shared__ u32 Wlds[2][8192];   // 64 KB: W2 / W3 bf16, swizzled

  const int tid = threadIdx.x;
  const int lane = tid & 63, lg = lane >> 4, lm = lane & 15;
  const int gs = (int)blockIdx.x * BLK + tid;   // this thread's sample

  float2 ab = ((const float2*)x)[gs];
  float* scat = out + 2 * BATCH;

#pragma unroll 1
  for(int i = 0; i < LNUM; ++i){
    const int parity = i & 1;
    const float sc = s_scale[i];
    const int off = i * WD, offW = i * (WD * WD);

    // ---------- phase A: s-MLP ----------
    __syncthreads();                       // previous phase done reading Wlds
    stage_W(sW2 + offW, Wlds[0], tid);
    stage_W(sW3 + offW, Wlds[1], tid);
    __syncthreads();
    const float u = parity ? ab.y : ab.x;
    float preS = mlp_frag(u, Wlds[0], Wlds[1], sW1 + off, sb1 + off,
                          sb2 + off, sb3 + off, sW4 + off, lm, lg) + sb4[i];
    const float sv = sc * tanhf(preS);
    scat[i * BATCH + gs] = sv;

    // ---------- phase B: t-MLP + coupling ----------
    __syncthreads();
    stage_W(tW2 + offW, Wlds[0], tid);
    stage_W(tW3 + offW, Wlds[1], tid);
    __syncthreads();
    float preT = mlp_frag(u, Wlds[0], Wlds[1], tW1 + off, tb1 + off,
                          tb2 + off, tb3 + off, tW4 + off, lm, lg) + tb4[i];
    const float tv = tanhf(preT);
    const float e = expf(sv);
    if(parity) ab.x = e * ab.x + tv; else ab.y = e * ab.y + tv;
  }

  ((float2*)out)[gs] = ab;
}

extern "C" void kernel_launch(void* const* d_in, const int* in_sizes, int n_in,
                              void* d_out, int out_size, void* d_ws, size_t ws_size,
                              hipStream_t stream) {
  (void)in_sizes; (void)n_in; (void)d_ws; (void)ws_size; (void)out_size;
  const float* p[18];
  for(int k = 0; k < 18; ++k) p[k] = (const float*)d_in[k];
  dim3 grid(BATCH / BLK), block(BLK);
  hipLaunchKernelGGL(flow_kernel, grid, block, 0, stream,
                     p[0], p[1], p[2], p[3], p[4], p[5], p[6], p[7], p[8], p[9],
                     p[10], p[11], p[12], p[13], p[14], p[15], p[16], p[17],
                     (float*)d_out);
}

// Round 5
// 2851.123 us; speedup vs baseline: 1.1365x; 1.1365x over previous
//
#include <hip/hip_runtime.h>

#define LNUM 8
#define WD 128
#define BATCH 262144
#define BLK 512

typedef unsigned int u32;
typedef __attribute__((ext_vector_type(8))) short bf16x8;
typedef __attribute__((ext_vector_type(4))) float f32x4;

// packed f32x2 -> bf16x2 (single VALU op)
__device__ __forceinline__ u32 pk2(float x, float y){
  u32 r;
  asm("v_cvt_pk_bf16_f32 %0, %1, %2" : "=v"(r) : "v"(x), "v"(y));
  return r;
}

// Stage a 128x128 fp32 weight matrix into LDS as bf16, row-major, XOR-swizzled
// (4-dword granularity: dword ^ ((row&7)<<2)). 512 threads: row j=t>>2, quarter q=t&3.
__device__ __forceinline__ void stage_W(const float* __restrict__ src, u32* dst, int tid){
  const int j = tid >> 2, q = tid & 3;
  const float* s = src + j * WD + q * 32;
  u32* drow = dst + j * 64;
  const int base = q * 16;
  const u32 sz = (u32)((j & 7) << 2);
#pragma unroll
  for(int c = 0; c < 4; ++c){
    float4 f0 = *(const float4*)(s + c * 8);
    float4 f1 = *(const float4*)(s + c * 8 + 4);
    uint4 w;
    w.x = pk2(f0.x, f0.y); w.y = pk2(f0.z, f0.w);
    w.z = pk2(f1.x, f1.y); w.w = pk2(f1.z, f1.w);
    *(uint4*)(drow + (((u32)(base + c * 4)) ^ sz)) = w;
  }
}

// One pass: full 4-stage MLP for 32 of the wave's 64 samples (st = st0, st0+1).
// Register-pressure-shaped: bv (stage-1 frags, 32 regs) and tr (H2, 32 regs) are
// the only long-lived arrays; per-jt accumulators are folded immediately.
// mid1 k-map: slot (lg,e) <-> k = kt*32+lg*8+e (A: b128).
// mid2 k-map: slot (lg,e) <-> k = kt*32+(e>>2)*16+lg*4+(e&3) -> B is the lane's
// OWN tr dwords; A reads W3 with the matching permutation (2x b64). Validated R4.
__device__ __forceinline__ void mlp_pass(
    float u, int st0, const u32* __restrict__ W2lds, const u32* __restrict__ W3lds,
    const float* __restrict__ W1, const float* __restrict__ b1,
    const float* __restrict__ b2, const float* __restrict__ b3,
    const float* __restrict__ W4, int lm, int lg, float* pout)
{
  const float us0 = __shfl(u, st0 * 16 + lm, 64);
  const float us1 = __shfl(u, st0 * 16 + 16 + lm, 64);

  // ---- stage 1: build B-fragments for both sample-tiles of this pass ----
  bf16x8 bv[4][2];
#pragma unroll
  for(int kt = 0; kt < 4; ++kt){
    const int ko = kt * 32 + lg * 8;
    const float4 w1a = *(const float4*)(W1 + ko);
    const float4 w1b = *(const float4*)(W1 + ko + 4);
    const float4 g1a = *(const float4*)(b1 + ko);
    const float4 g1b = *(const float4*)(b1 + ko + 4);
#pragma unroll
    for(int q = 0; q < 2; ++q){
      const float uv = q ? us1 : us0;
      uint4 pk;
      pk.x = pk2(fmaxf(fmaf(uv, w1a.x, g1a.x), 0.f), fmaxf(fmaf(uv, w1a.y, g1a.y), 0.f));
      pk.y = pk2(fmaxf(fmaf(uv, w1a.z, g1a.z), 0.f), fmaxf(fmaf(uv, w1a.w, g1a.w), 0.f));
      pk.z = pk2(fmaxf(fmaf(uv, w1b.x, g1b.x), 0.f), fmaxf(fmaf(uv, w1b.y, g1b.y), 0.f));
      pk.w = pk2(fmaxf(fmaf(uv, w1b.z, g1b.z), 0.f), fmaxf(fmaf(uv, w1b.w, g1b.w), 0.f));
      bv[kt][q] = __builtin_bit_cast(bf16x8, pk);
    }
  }

  // ---- mid1: per j-tile accumulate, fold into tr immediately ----
  u32 tr[8][2][2];
#pragma unroll
  for(int jt = 0; jt < 8; ++jt){
    const int j = lm + 16 * jt;
    const u32 sz = (u32)((j & 7) << 2);
    const u32* r = W2lds + j * 64;
    f32x4 a0 = {0.f,0.f,0.f,0.f}, a1 = {0.f,0.f,0.f,0.f};
#pragma unroll
    for(int kt = 0; kt < 4; ++kt){
      bf16x8 av = __builtin_bit_cast(bf16x8,
          *(const uint4*)(r + (((u32)(kt * 16 + lg * 4)) ^ sz)));
      a0 = __builtin_amdgcn_mfma_f32_16x16x32_bf16(av, bv[kt][0], a0, 0, 0, 0);
      a1 = __builtin_amdgcn_mfma_f32_16x16x32_bf16(av, bv[kt][1], a1, 0, 0, 0);
    }
    const float4 bb = *(const float4*)(b2 + jt * 16 + lg * 4);
    tr[jt][0][0] = pk2(fmaxf(a0[0] + bb.x, 0.f), fmaxf(a0[1] + bb.y, 0.f));
    tr[jt][0][1] = pk2(fmaxf(a0[2] + bb.z, 0.f), fmaxf(a0[3] + bb.w, 0.f));
    tr[jt][1][0] = pk2(fmaxf(a1[0] + bb.x, 0.f), fmaxf(a1[1] + bb.y, 0.f));
    tr[jt][1][1] = pk2(fmaxf(a1[2] + bb.z, 0.f), fmaxf(a1[3] + bb.w, 0.f));
  }

  // ---- mid2 + out: per j-tile accumulate, fold into stage-4 dot immediately ----
  float p0 = 0.f, p1 = 0.f;
#pragma unroll
  for(int jt = 0; jt < 8; ++jt){
    const int j = lm + 16 * jt;
    const u32 sz = (u32)((j & 7) << 2);
    const u32* r = W3lds + j * 64;
    f32x4 a0 = {0.f,0.f,0.f,0.f}, a1 = {0.f,0.f,0.f,0.f};
#pragma unroll
    for(int kt = 0; kt < 4; ++kt){
      const u32 o1 = (u32)(kt * 16 + 2 * lg);
      uint2 lo = *(const uint2*)(r + (o1 ^ sz));
      uint2 hi = *(const uint2*)(r + ((o1 + 8) ^ sz));
      uint4 a4; a4.x = lo.x; a4.y = lo.y; a4.z = hi.x; a4.w = hi.y;
      bf16x8 av = __builtin_bit_cast(bf16x8, a4);
      uint4 q0; q0.x = tr[2*kt][0][0]; q0.y = tr[2*kt][0][1];
      q0.z = tr[2*kt+1][0][0]; q0.w = tr[2*kt+1][0][1];
      uint4 q1; q1.x = tr[2*kt][1][0]; q1.y = tr[2*kt][1][1];
      q1.z = tr[2*kt+1][1][0]; q1.w = tr[2*kt+1][1][1];
      a0 = __builtin_amdgcn_mfma_f32_16x16x32_bf16(av, __builtin_bit_cast(bf16x8, q0), a0, 0, 0, 0);
      a1 = __builtin_amdgcn_mfma_f32_16x16x32_bf16(av, __builtin_bit_cast(bf16x8, q1), a1, 0, 0, 0);
    }
    const float4 bc = *(const float4*)(b3 + jt * 16 + lg * 4);
    const float4 wc = *(const float4*)(W4 + jt * 16 + lg * 4);
    p0 = fmaf(fmaxf(a0[0] + bc.x, 0.f), wc.x, p0);
    p0 = fmaf(fmaxf(a0[1] + bc.y, 0.f), wc.y, p0);
    p0 = fmaf(fmaxf(a0[2] + bc.z, 0.f), wc.z, p0);
    p0 = fmaf(fmaxf(a0[3] + bc.w, 0.f), wc.w, p0);
    p1 = fmaf(fmaxf(a1[0] + bc.x, 0.f), wc.x, p1);
    p1 = fmaf(fmaxf(a1[1] + bc.y, 0.f), wc.y, p1);
    p1 = fmaf(fmaxf(a1[2] + bc.z, 0.f), wc.z, p1);
    p1 = fmaf(fmaxf(a1[3] + bc.w, 0.f), wc.w, p1);
  }
  p0 += __shfl_xor(p0, 16, 64); p0 += __shfl_xor(p0, 32, 64);
  p1 += __shfl_xor(p1, 16, 64); p1 += __shfl_xor(p1, 32, 64);
  pout[0] = p0; pout[1] = p1;
}

__device__ __forceinline__ float mlp_full(
    float u, const u32* __restrict__ W2lds, const u32* __restrict__ W3lds,
    const float* __restrict__ W1, const float* __restrict__ b1,
    const float* __restrict__ b2, const float* __restrict__ b3,
    const float* __restrict__ W4, int lm, int lg)
{
  float pa[2], pb[2];
  mlp_pass(u, 0, W2lds, W3lds, W1, b1, b2, b3, W4, lm, lg, pa);
  mlp_pass(u, 2, W2lds, W3lds, W1, b1, b2, b3, W4, lm, lg, pb);
  // own sample's st index == lg
  return (lg == 0) ? pa[0] : (lg == 1) ? pa[1] : (lg == 2) ? pb[0] : pb[1];
}

extern "C" __global__ void __launch_bounds__(BLK, 4)
flow_kernel(const float* __restrict__ x, const float* __restrict__ s_scale,
            const float* __restrict__ sW1, const float* __restrict__ sb1,
            const float* __restrict__ sW2, const float* __restrict__ sb2,
            const float* __restrict__ sW3, const float* __restrict__ sb3,
            const float* __restrict__ sW4, const float* __restrict__ sb4,
            const float* __restrict__ tW1, const float* __restrict__ tb1,
            const float* __restrict__ tW2, const float* __restrict__ tb2,
            const float* __restrict__ tW3, const float* __restrict__ tb3,
            const float* __restrict__ tW4, const float* __restrict__ tb4,
            float* __restrict__ out)
{
  __shared__ u32 Wlds[2][8192];   // 64 KB: W2 / W3 bf16, swizzled

  const int tid = threadIdx.x;
  const int lane = tid & 63, lg = lane >> 4, lm = lane & 15;
  const int gs = (int)blockIdx.x * BLK + tid;   // this thread's sample

  float2 ab = ((const float2*)x)[gs];
  float* scat = out + 2 * BATCH;

#pragma unroll 1
  for(int i = 0; i < LNUM; ++i){
    const int parity = i & 1;
    const float sc = s_scale[i];
    const int off = i * WD, offW = i * (WD * WD);

    // ---------- phase A: s-MLP ----------
    __syncthreads();                       // previous phase done reading Wlds
    stage_W(sW2 + offW, Wlds[0], tid);
    stage_W(sW3 + offW, Wlds[1], tid);
    __syncthreads();
    const float u = parity ? ab.y : ab.x;
    float preS = mlp_full(u, Wlds[0], Wlds[1], sW1 + off, sb1 + off,
                          sb2 + off, sb3 + off, sW4 + off, lm, lg) + sb4[i];
    const float sv = sc * tanhf(preS);
    scat[i * BATCH + gs] = sv;

    // ---------- phase B: t-MLP + coupling ----------
    __syncthreads();
    stage_W(tW2 + offW, Wlds[0], tid);
    stage_W(tW3 + offW, Wlds[1], tid);
    __syncthreads();
    float preT = mlp_full(u, Wlds[0], Wlds[1], tW1 + off, tb1 + off,
                          tb2 + off, tb3 + off, tW4 + off, lm, lg) + tb4[i];
    const float tv = tanhf(preT);
    const float e = expf(sv);
    if(parity) ab.x = e * ab.x + tv; else ab.y = e * ab.y + tv;
  }

  ((float2*)out)[gs] = ab;
}

extern "C" void kernel_launch(void* const* d_in, const int* in_sizes, int n_in,
                              void* d_out, int out_size, void* d_ws, size_t ws_size,
                              hipStream_t stream) {
  (void)in_sizes; (void)n_in; (void)d_ws; (void)ws_size; (void)out_size;
  const float* p[18];
  for(int k = 0; k < 18; ++k) p[k] = (const float*)d_in[k];
  dim3 grid(BATCH / BLK), block(BLK);
  hipLaunchKernelGGL(flow_kernel, grid, block, 0, stream,
                     p[0], p[1], p[2], p[3], p[4], p[5], p[6], p[7], p[8], p[9],
                     p[10], p[11], p[12], p[13], p[14], p[15], p[16], p[17],
                     (float*)d_out);
}

// Round 6
// 639.260 us; speedup vs baseline: 5.0690x; 4.4600x over previous
//
#include <hip/hip_runtime.h>

#define LNUM 8
#define WD 128
#define BATCH 262144
#define BLK 512

typedef unsigned int u32;
typedef __attribute__((ext_vector_type(8))) short bf16x8;
typedef __attribute__((ext_vector_type(4))) float f32x4;

// packed f32x2 -> bf16x2 (single VALU op)
__device__ __forceinline__ u32 pk2(float x, float y){
  u32 r;
  asm("v_cvt_pk_bf16_f32 %0, %1, %2" : "=v"(r) : "v"(x), "v"(y));
  return r;
}

// Stage a 128x128 fp32 weight matrix into LDS as bf16, row-major, XOR-swizzled
// (4-dword granularity: dword ^ ((row&7)<<2)). 512 threads: row j=t>>2, quarter q=t&3.
__device__ __forceinline__ void stage_W(const float* __restrict__ src, u32* dst, int tid){
  const int j = tid >> 2, q = tid & 3;
  const float* s = src + j * WD + q * 32;
  u32* drow = dst + j * 64;
  const int base = q * 16;
  const u32 sz = (u32)((j & 7) << 2);
#pragma unroll
  for(int c = 0; c < 4; ++c){
    float4 f0 = *(const float4*)(s + c * 8);
    float4 f1 = *(const float4*)(s + c * 8 + 4);
    uint4 w;
    w.x = pk2(f0.x, f0.y); w.y = pk2(f0.z, f0.w);
    w.z = pk2(f1.x, f1.y); w.w = pk2(f1.z, f1.w);
    *(uint4*)(drow + (((u32)(base + c * 4)) ^ sz)) = w;
  }
}

// One pass: full 4-stage MLP for 32 of the wave's 64 samples (st = st0, st0+1).
// Register-pressure-shaped: bv (stage-1 frags, 32 regs) and tr (H2, 32 regs) are
// the only long-lived arrays; per-jt accumulators are folded immediately.
// mid1 k-map: slot (lg,e) <-> k = kt*32+lg*8+e (A: b128).
// mid2 k-map: slot (lg,e) <-> k = kt*32+(e>>2)*16+lg*4+(e&3) -> B is the lane's
// OWN tr dwords; A reads W3 with the matching permutation (2x b64). Validated R4/R5.
__device__ __forceinline__ float2 mlp_pass(
    float u, int st0, const u32* __restrict__ W2lds, const u32* __restrict__ W3lds,
    const float* __restrict__ W1, const float* __restrict__ b1,
    const float* __restrict__ b2, const float* __restrict__ b3,
    const float* __restrict__ W4, int lm, int lg)
{
  const float us0 = __shfl(u, st0 * 16 + lm, 64);
  const float us1 = __shfl(u, st0 * 16 + 16 + lm, 64);

  // ---- stage 1: build B-fragments for both sample-tiles of this pass ----
  bf16x8 bv[4][2];
#pragma unroll
  for(int kt = 0; kt < 4; ++kt){
    const int ko = kt * 32 + lg * 8;
    const float4 w1a = *(const float4*)(W1 + ko);
    const float4 w1b = *(const float4*)(W1 + ko + 4);
    const float4 g1a = *(const float4*)(b1 + ko);
    const float4 g1b = *(const float4*)(b1 + ko + 4);
#pragma unroll
    for(int q = 0; q < 2; ++q){
      const float uv = q ? us1 : us0;
      uint4 pk;
      pk.x = pk2(fmaxf(fmaf(uv, w1a.x, g1a.x), 0.f), fmaxf(fmaf(uv, w1a.y, g1a.y), 0.f));
      pk.y = pk2(fmaxf(fmaf(uv, w1a.z, g1a.z), 0.f), fmaxf(fmaf(uv, w1a.w, g1a.w), 0.f));
      pk.z = pk2(fmaxf(fmaf(uv, w1b.x, g1b.x), 0.f), fmaxf(fmaf(uv, w1b.y, g1b.y), 0.f));
      pk.w = pk2(fmaxf(fmaf(uv, w1b.z, g1b.z), 0.f), fmaxf(fmaf(uv, w1b.w, g1b.w), 0.f));
      bv[kt][q] = __builtin_bit_cast(bf16x8, pk);
    }
  }

  // ---- mid1: per j-tile accumulate, fold into tr immediately ----
  u32 tr[8][2][2];
#pragma unroll
  for(int jt = 0; jt < 8; ++jt){
    const int j = lm + 16 * jt;
    const u32 sz = (u32)((j & 7) << 2);
    const u32* r = W2lds + j * 64;
    f32x4 a0 = {0.f,0.f,0.f,0.f}, a1 = {0.f,0.f,0.f,0.f};
#pragma unroll
    for(int kt = 0; kt < 4; ++kt){
      bf16x8 av = __builtin_bit_cast(bf16x8,
          *(const uint4*)(r + (((u32)(kt * 16 + lg * 4)) ^ sz)));
      a0 = __builtin_amdgcn_mfma_f32_16x16x32_bf16(av, bv[kt][0], a0, 0, 0, 0);
      a1 = __builtin_amdgcn_mfma_f32_16x16x32_bf16(av, bv[kt][1], a1, 0, 0, 0);
    }
    const float4 bb = *(const float4*)(b2 + jt * 16 + lg * 4);
    tr[jt][0][0] = pk2(fmaxf(a0[0] + bb.x, 0.f), fmaxf(a0[1] + bb.y, 0.f));
    tr[jt][0][1] = pk2(fmaxf(a0[2] + bb.z, 0.f), fmaxf(a0[3] + bb.w, 0.f));
    tr[jt][1][0] = pk2(fmaxf(a1[0] + bb.x, 0.f), fmaxf(a1[1] + bb.y, 0.f));
    tr[jt][1][1] = pk2(fmaxf(a1[2] + bb.z, 0.f), fmaxf(a1[3] + bb.w, 0.f));
  }

  // ---- mid2 + out: per j-tile accumulate, fold into stage-4 dot immediately ----
  float p0 = 0.f, p1 = 0.f;
#pragma unroll
  for(int jt = 0; jt < 8; ++jt){
    const int j = lm + 16 * jt;
    const u32 sz = (u32)((j & 7) << 2);
    const u32* r = W3lds + j * 64;
    f32x4 a0 = {0.f,0.f,0.f,0.f}, a1 = {0.f,0.f,0.f,0.f};
#pragma unroll
    for(int kt = 0; kt < 4; ++kt){
      const u32 o1 = (u32)(kt * 16 + 2 * lg);
      uint2 lo = *(const uint2*)(r + (o1 ^ sz));
      uint2 hi = *(const uint2*)(r + ((o1 + 8) ^ sz));
      uint4 a4; a4.x = lo.x; a4.y = lo.y; a4.z = hi.x; a4.w = hi.y;
      bf16x8 av = __builtin_bit_cast(bf16x8, a4);
      uint4 q0; q0.x = tr[2*kt][0][0]; q0.y = tr[2*kt][0][1];
      q0.z = tr[2*kt+1][0][0]; q0.w = tr[2*kt+1][0][1];
      uint4 q1; q1.x = tr[2*kt][1][0]; q1.y = tr[2*kt][1][1];
      q1.z = tr[2*kt+1][1][0]; q1.w = tr[2*kt+1][1][1];
      a0 = __builtin_amdgcn_mfma_f32_16x16x32_bf16(av, __builtin_bit_cast(bf16x8, q0), a0, 0, 0, 0);
      a1 = __builtin_amdgcn_mfma_f32_16x16x32_bf16(av, __builtin_bit_cast(bf16x8, q1), a1, 0, 0, 0);
    }
    const float4 bc = *(const float4*)(b3 + jt * 16 + lg * 4);
    const float4 wc = *(const float4*)(W4 + jt * 16 + lg * 4);
    p0 = fmaf(fmaxf(a0[0] + bc.x, 0.f), wc.x, p0);
    p0 = fmaf(fmaxf(a0[1] + bc.y, 0.f), wc.y, p0);
    p0 = fmaf(fmaxf(a0[2] + bc.z, 0.f), wc.z, p0);
    p0 = fmaf(fmaxf(a0[3] + bc.w, 0.f), wc.w, p0);
    p1 = fmaf(fmaxf(a1[0] + bc.x, 0.f), wc.x, p1);
    p1 = fmaf(fmaxf(a1[1] + bc.y, 0.f), wc.y, p1);
    p1 = fmaf(fmaxf(a1[2] + bc.z, 0.f), wc.z, p1);
    p1 = fmaf(fmaxf(a1[3] + bc.w, 0.f), wc.w, p1);
  }
  p0 += __shfl_xor(p0, 16, 64); p0 += __shfl_xor(p0, 32, 64);
  p1 += __shfl_xor(p1, 16, 64); p1 += __shfl_xor(p1, 32, 64);
  return make_float2(p0, p1);
}

__device__ __forceinline__ float mlp_full(
    float u, const u32* __restrict__ W2lds, const u32* __restrict__ W3lds,
    const float* __restrict__ W1, const float* __restrict__ b1,
    const float* __restrict__ b2, const float* __restrict__ b3,
    const float* __restrict__ W4, int lm, int lg)
{
  float2 pa = mlp_pass(u, 0, W2lds, W3lds, W1, b1, b2, b3, W4, lm, lg);
  float2 pb = mlp_pass(u, 2, W2lds, W3lds, W1, b1, b2, b3, W4, lm, lg);
  // own sample's st index == lg
  return (lg == 0) ? pa.x : (lg == 1) ? pa.y : (lg == 2) ? pb.x : pb.y;
}

extern "C" __global__ void __launch_bounds__(BLK, 2)
flow_kernel(const float* __restrict__ x, const float* __restrict__ s_scale,
            const float* __restrict__ sW1, const float* __restrict__ sb1,
            const float* __restrict__ sW2, const float* __restrict__ sb2,
            const float* __restrict__ sW3, const float* __restrict__ sb3,
            const float* __restrict__ sW4, const float* __restrict__ sb4,
            const float* __restrict__ tW1, const float* __restrict__ tb1,
            const float* __restrict__ tW2, const float* __restrict__ tb2,
            const float* __restrict__ tW3, const float* __restrict__ tb3,
            const float* __restrict__ tW4, const float* __restrict__ tb4,
            float* __restrict__ out)
{
  __shared__ u32 Wlds[2][8192];   // 64 KB: W2 / W3 bf16, swizzled

  const int tid = threadIdx.x;
  const int lane = tid & 63, lg = lane >> 4, lm = lane & 15;
  const int gs = (int)blockIdx.x * BLK + tid;   // this thread's sample

  float2 ab = ((const float2*)x)[gs];
  float* scat = out + 2 * BATCH;

#pragma unroll 1
  for(int i = 0; i < LNUM; ++i){
    const int parity = i & 1;
    const float sc = s_scale[i];
    const int off = i * WD, offW = i * (WD * WD);

    // ---------- phase A: s-MLP ----------
    __syncthreads();                       // previous phase done reading Wlds
    stage_W(sW2 + offW, Wlds[0], tid);
    stage_W(sW3 + offW, Wlds[1], tid);
    __syncthreads();
    const float u = parity ? ab.y : ab.x;
    float preS = mlp_full(u, Wlds[0], Wlds[1], sW1 + off, sb1 + off,
                          sb2 + off, sb3 + off, sW4 + off, lm, lg) + sb4[i];
    const float sv = sc * tanhf(preS);
    scat[i * BATCH + gs] = sv;

    // ---------- phase B: t-MLP + coupling ----------
    __syncthreads();
    stage_W(tW2 + offW, Wlds[0], tid);
    stage_W(tW3 + offW, Wlds[1], tid);
    __syncthreads();
    float preT = mlp_full(u, Wlds[0], Wlds[1], tW1 + off, tb1 + off,
                          tb2 + off, tb3 + off, tW4 + off, lm, lg) + tb4[i];
    const float tv = tanhf(preT);
    const float e = expf(sv);
    if(parity) ab.x = e * ab.x + tv; else ab.y = e * ab.y + tv;
  }

  ((float2*)out)[gs] = ab;
}

extern "C" void kernel_launch(void* const* d_in, const int* in_sizes, int n_in,
                              void* d_out, int out_size, void* d_ws, size_t ws_size,
                              hipStream_t stream) {
  (void)in_sizes; (void)n_in; (void)d_ws; (void)ws_size; (void)out_size;
  const float* p[18];
  for(int k = 0; k < 18; ++k) p[k] = (const float*)d_in[k];
  dim3 grid(BATCH / BLK), block(BLK);
  hipLaunchKernelGGL(flow_kernel, grid, block, 0, stream,
                     p[0], p[1], p[2], p[3], p[4], p[5], p[6], p[7], p[8], p[9],
                     p[10], p[11], p[12], p[13], p[14], p[15], p[16], p[17],
                     (float*)d_out);
}